// Round 5
// baseline (50.974 us; speedup 1.0000x reference)
//
#include <hip/hip_runtime.h>
#include <math.h>

// DOSAConLoss: out = mean(base) * (1 + 1.5*(N/max_hist)/1024)
//   base_i = (1 - ciou_i)^3 / (target_area_i + 1e-7)
//   (sum(hist) == N exactly, so mean(density_weight) needs only max_hist)
//
// R5 = R4 (wave-private LDS hist, u16 non-atomic partial flush, grid-stride,
// 1-atan + v_rcp math) with DOUBLED residency: 2048 blocks + launch_bounds(256,8)
// -> 8 blocks/CU, 32 waves/CU, 2x outstanding loads. Latency-bound fix.

#define NBLK 2048
#define BLOCK 256
#define GRID_BINS 1024

__device__ __forceinline__ float rcpf(float x) { return __builtin_amdgcn_rcpf(x); }

// |err| < ~2e-6 over full range; tolerance is ~2% of the output scalar.
__device__ __forceinline__ float fast_atan(float x) {
    float ax = fabsf(x);
    bool big = ax > 1.0f;
    float t = big ? rcpf(ax) : ax;
    float s = t * t;
    float p = -0.0117212f;
    p = __builtin_fmaf(p, s, 0.05265332f);
    p = __builtin_fmaf(p, s, -0.11643287f);
    p = __builtin_fmaf(p, s, 0.19354346f);
    p = __builtin_fmaf(p, s, -0.33262347f);
    p = __builtin_fmaf(p, s, 0.99997726f);
    float r = t * p;
    r = big ? 1.57079632679f - r : r;
    return copysignf(r, x);
}

__device__ __forceinline__ float ciou_base(float4 p, float4 t, unsigned* whist) {
    float x1 = p.x, y1 = p.y, w1 = p.z, h1 = p.w;
    float x2 = t.x, y2 = t.y, w2 = t.z, h2 = t.w;
    float b1x1 = x1 - w1 * 0.5f, b1x2 = x1 + w1 * 0.5f;
    float b1y1 = y1 - h1 * 0.5f, b1y2 = y1 + h1 * 0.5f;
    float b2x1 = x2 - w2 * 0.5f, b2x2 = x2 + w2 * 0.5f;
    float b2y1 = y2 - h2 * 0.5f, b2y2 = y2 + h2 * 0.5f;
    float iw = fmaxf(fminf(b1x2, b2x2) - fmaxf(b1x1, b2x1), 0.0f);
    float ih = fmaxf(fminf(b1y2, b2y2) - fmaxf(b1y1, b2y1), 0.0f);
    float inter = iw * ih;
    float uni = w1 * h1 + w2 * h2 - inter + 1e-7f;
    float iou = inter * rcpf(uni);
    float cw = fmaxf(b1x2, b2x2) - fminf(b1x1, b2x1);
    float ch = fmaxf(b1y2, b2y2) - fminf(b1y1, b2y1);
    float c2 = cw * cw + ch * ch + 1e-7f;
    float ddx = b2x1 + b2x2 - b1x1 - b1x2;
    float ddy = b2y1 + b2y2 - b1y1 - b1y2;
    float rho2 = (ddx * ddx + ddy * ddy) * 0.25f;
    // atan(w2/h2) - atan(w1/h1) == atan((w2*h1 - w1*h2)/(h1*h2 + w1*w2)); both in (0,pi/2)
    float dv = fast_atan((w2 * h1 - w1 * h2) * rcpf(h1 * h2 + w1 * w2));
    float v = 0.4052847345693511f * (dv * dv);
    float a = v * rcpf(v - iou + (1.0f + 1e-7f));
    float ciou = iou - (rho2 * rcpf(c2) + v * a);
    float om = 1.0f - ciou;
    int gx = min(max((int)(x2 * 32.0f), 0), 31);
    int gy = min(max((int)(y2 * 32.0f), 0), 31);
    atomicAdd(&whist[gy * 32 + gx], 1u);
    return om * om * om * rcpf(w2 * h2 + 1e-7f);
}

__global__ __launch_bounds__(BLOCK, 8) void dosa_main(
    const float4* __restrict__ pred, const float4* __restrict__ tgt, int n,
    unsigned short* __restrict__ partHist, double* __restrict__ partSum)
{
    __shared__ unsigned lhist[4][GRID_BINS];   // one histogram per wave
    __shared__ double wsum[BLOCK / 64];
    for (int i = threadIdx.x; i < 4 * GRID_BINS; i += BLOCK)
        lhist[i >> 10][i & 1023] = 0u;
    __syncthreads();

    const int wid = threadIdx.x >> 6;
    unsigned* whist = lhist[wid];

    const int T = NBLK * BLOCK;  // 524288
    float fsum = 0.0f;
    for (int i = blockIdx.x * BLOCK + threadIdx.x; i < n; i += T) {
        float4 p = pred[i];
        float4 t = tgt[i];
        fsum += ciou_base(p, t, whist);
    }

    // wave-level f32 reduce, then block double reduce
    for (int off = 32; off > 0; off >>= 1)
        fsum += __shfl_down(fsum, off, 64);
    int lane = threadIdx.x & 63;
    if (lane == 0) wsum[wid] = (double)fsum;
    __syncthreads();
    // sum the 4 wave-histograms, non-atomic u16 flush (coalesced, 2KB/block)
    for (int b = threadIdx.x; b < GRID_BINS; b += BLOCK) {
        unsigned c = lhist[0][b] + lhist[1][b] + lhist[2][b] + lhist[3][b];
        partHist[(size_t)blockIdx.x * GRID_BINS + b] = (unsigned short)c;
    }
    if (threadIdx.x == 0) {
        double s = 0.0;
        for (int w = 0; w < BLOCK / 64; ++w) s += wsum[w];
        partSum[blockIdx.x] = s;
    }
}

// 64 blocks; block handles 16 consecutive bins; 16 row-groups stream the 2048 partials.
__global__ __launch_bounds__(BLOCK) void dosa_hist_max(
    const unsigned short* __restrict__ partHist, unsigned* __restrict__ blockMax)
{
    __shared__ unsigned red[BLOCK];
    const int b0 = blockIdx.x * 16;
    const int binOff = threadIdx.x & 15;
    const int rgrp = threadIdx.x >> 4;
    unsigned s = 0;
    for (int r = rgrp; r < NBLK; r += 16)
        s += partHist[(size_t)r * GRID_BINS + b0 + binOff];
    red[threadIdx.x] = s;
    __syncthreads();
    for (int off = 128; off >= 16; off >>= 1) {
        if (threadIdx.x < off) red[threadIdx.x] += red[threadIdx.x + off];
        __syncthreads();
    }
    if (threadIdx.x == 0) {
        unsigned m = 0;
        for (int j = 0; j < 16; ++j) m = max(m, red[j]);
        blockMax[blockIdx.x] = m;
    }
}

__global__ __launch_bounds__(1024) void dosa_final(
    const unsigned* __restrict__ blockMax, const double* __restrict__ partSum,
    float* __restrict__ out, int n)
{
    __shared__ unsigned sm[1024];
    __shared__ double sd[1024];
    int t = threadIdx.x;
    sm[t] = (t < 64) ? blockMax[t] : 0u;
    sd[t] = partSum[t] + partSum[t + 1024];
    __syncthreads();
    for (int off = 512; off > 0; off >>= 1) {
        if (t < off) {
            sm[t] = max(sm[t], sm[t + off]);
            sd[t] += sd[t + off];
        }
        __syncthreads();
    }
    if (t == 0) {
        double meanBase = sd[0] / (double)n;
        double meanW = 1.0 + 1.5 * ((double)n / (double)sm[0]) / 1024.0;
        out[0] = (float)(meanBase * meanW);
    }
}

extern "C" void kernel_launch(void* const* d_in, const int* in_sizes, int n_in,
                              void* d_out, int out_size, void* d_ws, size_t ws_size,
                              hipStream_t stream) {
    const float4* pred = (const float4*)d_in[0];
    const float4* tgt  = (const float4*)d_in[1];
    int n = in_sizes[0] / 4;

    unsigned short* partHist = (unsigned short*)d_ws;                          // 4 MB
    double* partSum = (double*)((char*)d_ws + (size_t)NBLK * GRID_BINS * 2);   // 16 KB
    unsigned* blockMax = (unsigned*)((char*)partSum + NBLK * sizeof(double));  // 256 B
    float* out = (float*)d_out;

    dosa_main<<<NBLK, BLOCK, 0, stream>>>(pred, tgt, n, partHist, partSum);
    dosa_hist_max<<<64, BLOCK, 0, stream>>>(partHist, blockMax);
    dosa_final<<<1, 1024, 0, stream>>>(blockMax, partSum, out, n);
}

// Round 6
// 35.100 us; speedup vs baseline: 1.4523x; 1.4523x over previous
//
#include <hip/hip_runtime.h>
#include <math.h>

// DOSAConLoss: out = mean(base) * (1 + 1.5*(N/max_hist)/1024)
//   base_i = (1 - ciou_i)^3 / (target_area_i + 1e-7)
//   (sum(hist) == N exactly, so only max_hist is needed for the density term)
//
// R6: attack memory-latency wall with forced per-wave MLP: 4 float4-pairs
// loaded into named regs, sched_barrier(0) pins loads before compute
// (R3's array version was silently sunk by the compiler, VGPR=20..40).
// Epilogue K2 rewritten parallel (16 unrolled independent loads/thread) --
// R4/R5's 64-128-deep serial dependent-load loop was costing 15-30us.

#define NBLK 1024
#define BLOCK 512
#define GRID_BINS 1024

__device__ __forceinline__ float rcpf(float x) { return __builtin_amdgcn_rcpf(x); }

// |err| < ~2e-6 over full range; tolerance is ~2% of the output scalar.
__device__ __forceinline__ float fast_atan(float x) {
    float ax = fabsf(x);
    bool big = ax > 1.0f;
    float t = big ? rcpf(ax) : ax;
    float s = t * t;
    float p = -0.0117212f;
    p = __builtin_fmaf(p, s, 0.05265332f);
    p = __builtin_fmaf(p, s, -0.11643287f);
    p = __builtin_fmaf(p, s, 0.19354346f);
    p = __builtin_fmaf(p, s, -0.33262347f);
    p = __builtin_fmaf(p, s, 0.99997726f);
    float r = t * p;
    r = big ? 1.57079632679f - r : r;
    return copysignf(r, x);
}

__device__ __forceinline__ float ciou_base(float4 p, float4 t, unsigned* lhist, bool valid) {
    float x1 = p.x, y1 = p.y, w1 = p.z, h1 = p.w;
    float x2 = t.x, y2 = t.y, w2 = t.z, h2 = t.w;
    float b1x1 = x1 - w1 * 0.5f, b1x2 = x1 + w1 * 0.5f;
    float b1y1 = y1 - h1 * 0.5f, b1y2 = y1 + h1 * 0.5f;
    float b2x1 = x2 - w2 * 0.5f, b2x2 = x2 + w2 * 0.5f;
    float b2y1 = y2 - h2 * 0.5f, b2y2 = y2 + h2 * 0.5f;
    float iw = fmaxf(fminf(b1x2, b2x2) - fmaxf(b1x1, b2x1), 0.0f);
    float ih = fmaxf(fminf(b1y2, b2y2) - fmaxf(b1y1, b2y1), 0.0f);
    float inter = iw * ih;
    float uni = w1 * h1 + w2 * h2 - inter + 1e-7f;
    float iou = inter * rcpf(uni);
    float cw = fmaxf(b1x2, b2x2) - fminf(b1x1, b2x1);
    float ch = fmaxf(b1y2, b2y2) - fminf(b1y1, b2y1);
    float c2 = cw * cw + ch * ch + 1e-7f;
    float ddx = b2x1 + b2x2 - b1x1 - b1x2;
    float ddy = b2y1 + b2y2 - b1y1 - b1y2;
    float rho2 = (ddx * ddx + ddy * ddy) * 0.25f;
    // atan(w2/h2) - atan(w1/h1) == atan((w2*h1 - w1*h2)/(h1*h2 + w1*w2)); both in (0,pi/2)
    float dv = fast_atan((w2 * h1 - w1 * h2) * rcpf(h1 * h2 + w1 * w2));
    float v = 0.4052847345693511f * (dv * dv);
    float a = v * rcpf(v - iou + (1.0f + 1e-7f));
    float ciou = iou - (rho2 * rcpf(c2) + v * a);
    float om = 1.0f - ciou;
    int gx = min(max((int)(x2 * 32.0f), 0), 31);
    int gy = min(max((int)(y2 * 32.0f), 0), 31);
    if (valid) atomicAdd(&lhist[gy * 32 + gx], 1u);
    float base = om * om * om * rcpf(w2 * h2 + 1e-7f);
    return valid ? base : 0.0f;
}

__global__ __launch_bounds__(BLOCK) void dosa_main(
    const float4* __restrict__ pred, const float4* __restrict__ tgt, int n,
    unsigned short* __restrict__ partHist, double* __restrict__ partSum)
{
    __shared__ unsigned lhist[GRID_BINS];
    __shared__ double wsum[BLOCK / 64];
    for (int i = threadIdx.x; i < GRID_BINS; i += BLOCK) lhist[i] = 0u;
    __syncthreads();

    const int T = NBLK * BLOCK;  // 524288
    const int i0 = blockIdx.x * BLOCK + threadIdx.x;
    float fsum = 0.0f;

    // ---- group 1: elements 0..3 (always valid: i0+3T < 4e6) ----
    float4 p0 = pred[i0 + 0 * T], q0 = tgt[i0 + 0 * T];
    float4 p1 = pred[i0 + 1 * T], q1 = tgt[i0 + 1 * T];
    float4 p2 = pred[i0 + 2 * T], q2 = tgt[i0 + 2 * T];
    float4 p3 = pred[i0 + 3 * T], q3 = tgt[i0 + 3 * T];
    __builtin_amdgcn_sched_barrier(0);   // pin: all 8 loads issued before compute
    fsum += ciou_base(p0, q0, lhist, true);
    fsum += ciou_base(p1, q1, lhist, true);
    fsum += ciou_base(p2, q2, lhist, true);
    fsum += ciou_base(p3, q3, lhist, true);

    // ---- group 2: elements 4..6 valid, 7 guarded ----
    const bool v7 = (i0 + 7 * T) < n;
    const int i7 = v7 ? (i0 + 7 * T) : i0;
    float4 p4 = pred[i0 + 4 * T], q4 = tgt[i0 + 4 * T];
    float4 p5 = pred[i0 + 5 * T], q5 = tgt[i0 + 5 * T];
    float4 p6 = pred[i0 + 6 * T], q6 = tgt[i0 + 6 * T];
    float4 p7 = pred[i7],         q7 = tgt[i7];
    __builtin_amdgcn_sched_barrier(0);
    fsum += ciou_base(p4, q4, lhist, true);
    fsum += ciou_base(p5, q5, lhist, true);
    fsum += ciou_base(p6, q6, lhist, true);
    fsum += ciou_base(p7, q7, lhist, v7);

    // wave-level f32 reduce, then block double reduce
    for (int off = 32; off > 0; off >>= 1)
        fsum += __shfl_down(fsum, off, 64);
    int lane = threadIdx.x & 63;
    int wid = threadIdx.x >> 6;
    if (lane == 0) wsum[wid] = (double)fsum;
    __syncthreads();
    // non-atomic u16 partial flush (coalesced, 2KB/block; max count 4096 < 65536)
    for (int b = threadIdx.x; b < GRID_BINS; b += BLOCK)
        partHist[(size_t)blockIdx.x * GRID_BINS + b] = (unsigned short)lhist[b];
    if (threadIdx.x == 0) {
        double s = 0.0;
        for (int w = 0; w < BLOCK / 64; ++w) s += wsum[w];
        partSum[blockIdx.x] = s;
    }
}

// 64 blocks x 1024 threads; block owns 16 bins. tid = rowgrp*16 + binoff;
// each thread sums 16 rows (stride 64) -- 16 INDEPENDENT unrolled loads,
// then LDS tree over the 64 row-groups. No serial dependent-load chain.
__global__ __launch_bounds__(1024) void dosa_hist_max(
    const unsigned short* __restrict__ partHist, unsigned* __restrict__ blockMax)
{
    __shared__ unsigned red[1024];
    const int b0 = blockIdx.x * 16;
    const int binOff = threadIdx.x & 15;
    const int rowgrp = threadIdx.x >> 4;   // 0..63
    unsigned s = 0;
#pragma unroll
    for (int k = 0; k < NBLK / 64; ++k)
        s += partHist[(size_t)(rowgrp + k * 64) * GRID_BINS + b0 + binOff];
    red[threadIdx.x] = s;
    __syncthreads();
    for (int off = 512; off >= 16; off >>= 1) {
        if (threadIdx.x < off) red[threadIdx.x] += red[threadIdx.x + off];
        __syncthreads();
    }
    if (threadIdx.x == 0) {
        unsigned m = 0;
        for (int j = 0; j < 16; ++j) m = max(m, red[j]);
        blockMax[blockIdx.x] = m;
    }
}

__global__ __launch_bounds__(1024) void dosa_final(
    const unsigned* __restrict__ blockMax, const double* __restrict__ partSum,
    float* __restrict__ out, int n)
{
    __shared__ unsigned sm[1024];
    __shared__ double sd[1024];
    int t = threadIdx.x;
    sm[t] = (t < 64) ? blockMax[t] : 0u;
    sd[t] = partSum[t];
    __syncthreads();
    for (int off = 512; off > 0; off >>= 1) {
        if (t < off) {
            sm[t] = max(sm[t], sm[t + off]);
            sd[t] += sd[t + off];
        }
        __syncthreads();
    }
    if (t == 0) {
        double meanBase = sd[0] / (double)n;
        double meanW = 1.0 + 1.5 * ((double)n / (double)sm[0]) / 1024.0;
        out[0] = (float)(meanBase * meanW);
    }
}

extern "C" void kernel_launch(void* const* d_in, const int* in_sizes, int n_in,
                              void* d_out, int out_size, void* d_ws, size_t ws_size,
                              hipStream_t stream) {
    const float4* pred = (const float4*)d_in[0];
    const float4* tgt  = (const float4*)d_in[1];
    int n = in_sizes[0] / 4;

    unsigned short* partHist = (unsigned short*)d_ws;                          // 2 MB
    double* partSum = (double*)((char*)d_ws + (size_t)NBLK * GRID_BINS * 2);   // 8 KB
    unsigned* blockMax = (unsigned*)((char*)partSum + NBLK * sizeof(double));  // 256 B
    float* out = (float*)d_out;

    dosa_main<<<NBLK, BLOCK, 0, stream>>>(pred, tgt, n, partHist, partSum);
    dosa_hist_max<<<64, 1024, 0, stream>>>(partHist, blockMax);
    dosa_final<<<1, 1024, 0, stream>>>(blockMax, partSum, out, n);
}